// Round 12
// baseline (94.792 us; speedup 1.0000x reference)
//
#include <hip/hip_runtime.h>
#include <math.h>

#define BB 32
#define NN 512
#define NFEAT 128
#define NHID 8
#define NHEADS 8
#define LALPHA 0.2f

__device__ __forceinline__ float elu1(float x)  { return x > 0.f ? x : __expf(x) - 1.f; }

// monotone float -> uint mapping (total order refines float order); ok(-v) == ~ok(v)
__device__ __forceinline__ unsigned ordkey(float v) {
    unsigned u = __float_as_uint(v);
    return u ^ (((unsigned)((int)u >> 31)) | 0x80000000u);
}
__device__ __forceinline__ float unord(unsigned k) {
    unsigned u = (k & 0x80000000u) ? (k ^ 0x80000000u) : ~k;
    return __uint_as_float(u);
}

// inclusive 64-lane add-scan: 6 DPP ops (VALU pipe only).
#if __has_builtin(__builtin_amdgcn_update_dpp)
__device__ __forceinline__ float wscan(float x, int lane) {
    int y;
    y = __builtin_amdgcn_update_dpp(0, __float_as_int(x), 0x111, 0xF, 0xF, true); x += __int_as_float(y);
    y = __builtin_amdgcn_update_dpp(0, __float_as_int(x), 0x112, 0xF, 0xF, true); x += __int_as_float(y);
    y = __builtin_amdgcn_update_dpp(0, __float_as_int(x), 0x114, 0xF, 0xF, true); x += __int_as_float(y);
    y = __builtin_amdgcn_update_dpp(0, __float_as_int(x), 0x118, 0xF, 0xF, true); x += __int_as_float(y);
    y = __builtin_amdgcn_update_dpp(0, __float_as_int(x), 0x142, 0xA, 0xF, true); x += __int_as_float(y);
    y = __builtin_amdgcn_update_dpp(0, __float_as_int(x), 0x143, 0xC, 0xF, true); x += __int_as_float(y);
    return x;
}
#else
__device__ __forceinline__ float wscan(float x, int lane) {
    #pragma unroll
    for (int s = 1; s < 64; s <<= 1) {
        float y = __shfl_up(x, (unsigned)s, 64);
        x += (lane >= s) ? y : 0.f;
    }
    return x;
}
#endif

__device__ __forceinline__ unsigned long long shflxor64(unsigned long long x, int j) {
    unsigned lo = (unsigned)__shfl_xor((int)(unsigned)x, j, 64);
    unsigned hw = (unsigned)__shfl_xor((int)(unsigned)(x >> 32), j, 64);
    return (((unsigned long long)hw) << 32) | lo;
}

// full in-wave bitonic sort of 64 u64 keys (ascending across lanes), register-only
__device__ __forceinline__ unsigned long long wsort64(unsigned long long x, int lane) {
    #pragma unroll
    for (int k = 2; k <= 64; k <<= 1) {
        #pragma unroll
        for (int j = k >> 1; j >= 1; j >>= 1) {
            unsigned long long y = shflxor64(x, j);
            const bool takeMin = ((lane & j) == 0) == ((lane & k) == 0);
            const bool sw = takeMin ? (y < x) : (x < y);
            x = sw ? y : x;
        }
    }
    return x;
}

// guarded branchless lower bounds (can return the full length)
__device__ __forceinline__ int lb64u(const unsigned long long* a, unsigned long long v) {
    int lo = 0;
    #pragma unroll
    for (int s = 64; s >= 1; s >>= 1) {
        const int i2 = lo + s - 1;
        if (i2 < 64 && a[i2] < v) lo += s;
    }
    return lo;
}
__device__ __forceinline__ int lb512u(const unsigned long long* a, unsigned long long v) {
    int lo = 0;
    #pragma unroll
    for (int s = NN; s >= 1; s >>= 1) {
        const int i2 = lo + s - 1;
        if (i2 < NN && a[i2] < v) lo += s;
    }
    return lo;
}

// global rank of x within the 8 sorted 64-runs (own run = wr, own pos = lane)
__device__ __forceinline__ int rank512(const unsigned long long* runs, unsigned long long x,
                                       int wr, int lane) {
    int rk = lane;
    #pragma unroll
    for (int w2 = 0; w2 < 8; ++w2)
        if (w2 != wr) rk += lb64u(runs + 64 * w2, x);
    return rk;
}

// Fused layer-1 GAT per (b,h). x2 output is head-major: x2[h][b][n][8].
// LDS deliberately sized 84.5 KB (> 80 KB): only ONE block fits per CU, so the
// register allocator budgets 128 VGPRs (4 waves/SIMD) instead of capping at 64
// and spilling ~85 floats/thread to scratch (rounds 8-11 pathology: 167 MB FETCH).
__global__ __launch_bounds__(1024) void k12_gat1(
        const float* __restrict__ nf, const float* __restrict__ Ws,
        const float* __restrict__ As, float* __restrict__ x2)
{
    __shared__ __align__(16) float WT[NHID * NFEAT];           // transposed W [d][f], 4 KB
    __shared__ float aL[16];
    __shared__ __align__(16) float whL[NN][NHID];              // 16 KB
    __shared__ __align__(16) float s1L[NN], s2L[NN];           // 4 KB
    __shared__ __align__(16) unsigned long long key1L[NN];     // 4 KB (sorted s1 keys)
    __shared__ __align__(16) unsigned long long key2L[NN];     // 4 KB (sorted s2 keys)
    __shared__ __align__(16) unsigned long long keyR1[NN + 256]; // 6 KB (8 sorted runs + occupancy pad)
    __shared__ __align__(16) unsigned long long keyR2[NN + 256]; // 6 KB
    __shared__ float prefP[NN], prefQ[NN], denS[NN];           // 6 KB
    __shared__ __align__(16) float PP[NN][NHID];               // 16 KB
    __shared__ __align__(16) float QQ[NN][NHID];               // 16 KB
    __shared__ __align__(16) float wvT[16][NHID];              // 0.5 KB
    // total ~84.5 KB > 80 KB -> 1 block/CU

    const int blk = blockIdx.x;
    const int b = blk & 31, h = blk >> 5;   // same-b blocks share an XCD (blk%8 == b%8)
    const int t = threadIdx.x;
    const int r = t & (NN - 1);
    const bool hi = t >= NN;
    const int lane = t & 63, w = t >> 6;
    const int wr = w & 7;
    const int cs = lane & 7;                // column-segment within row group

    {
        const int f = t >> 3, d = t & 7;
        WT[d * NFEAT + f] = Ws[(size_t)h * NFEAT * NHID + t];
    }
    if (t < 16) aL[t] = As[h * 16 + t];
    __syncthreads();                                           // B1

    // ---- matmul: 4 passes, each wave = 8 rows, 8 lanes/row, coalesced 128B segments ----
    {
        const float4* nf4 = (const float4*)nf;
        const float4* WT4 = (const float4*)WT;
        #pragma unroll 2
        for (int pass = 0; pass < 4; ++pass) {
            const int row = pass * 128 + w * 8 + (lane >> 3);
            float acc[NHID];
            #pragma unroll
            for (int d = 0; d < NHID; ++d) acc[d] = 0.f;
            const int rb = (b * NN + row) * 32;
            #pragma unroll
            for (int i = 0; i < 4; ++i) {
                const float4 v = nf4[rb + cs + 8 * i];
                #pragma unroll
                for (int d = 0; d < NHID; ++d) {
                    const float4 wv = WT4[d * 32 + cs + 8 * i];
                    acc[d] += v.x * wv.x + v.y * wv.y + v.z * wv.z + v.w * wv.w;
                }
            }
            #pragma unroll
            for (int s = 1; s <= 4; s <<= 1) {
                #pragma unroll
                for (int d = 0; d < NHID; ++d) acc[d] += __shfl_xor(acc[d], s, 64);
            }
            if (cs == 0) {
                float4* wrp = (float4*)&whL[row][0];
                wrp[0] = make_float4(acc[0], acc[1], acc[2], acc[3]);
                wrp[1] = make_float4(acc[4], acc[5], acc[6], acc[7]);
                float a1 = 0.f;
                #pragma unroll
                for (int d = 0; d < NHID; ++d) a1 += acc[d] * aL[d];
                s1L[row] = a1;
            } else if (cs == 1) {
                float a2 = 0.f;
                #pragma unroll
                for (int d = 0; d < NHID; ++d) a2 += acc[d] * aL[8 + d];
                s2L[row] = a2;
            }
        }
    }
    __syncthreads();                                           // B2

    // ---- wave-local sorts: P sorts s1 keys, H sorts s2 keys ----
    float v1 = 0.f;
    unsigned long long sk;
    if (!hi) {
        v1 = s1L[t];
        sk = (((unsigned long long)ordkey(v1)) << 9) | (unsigned)t;
    } else {
        sk = (((unsigned long long)ordkey(s2L[r])) << 9) | (unsigned)r;
    }
    sk = wsort64(sk, lane);
    if (!hi) keyR1[t] = sk; else keyR2[r] = sk;
    __syncthreads();                                           // B3

    {
        const unsigned long long* runs = hi ? keyR2 : keyR1;
        const int rk = rank512(runs, sk, wr, lane);
        if (!hi) key1L[rk] = sk; else key2L[rk] = sk;
    }
    __syncthreads();                                           // B4

    // ---- P: exp scans + c4; H: sorted element, payload gather + kH ----
    float ps = 0.f, qs = 0.f;
    float who[NHID];
    float s2r = 0.f, e2p = 0.f, e2q = 0.f, e1p = 0.f, e1q = 0.f;
    int kH = 0, c4 = 0;
    if (!hi) {
        const float s1v = unord((unsigned)(key1L[t] >> 9));
        ps = wscan(__expf(s1v), lane);
        qs = wscan(__expf(LALPHA * s1v), lane);
        if (lane == 63) { wvT[w][0] = ps; wvT[w][1] = qs; }
        c4 = lb512u(key2L, ((unsigned long long)(~ordkey(v1))) << 9);
        e1p = __expf(v1); e1q = __expf(LALPHA * v1);
    } else {
        const unsigned long long k2 = key2L[r];
        s2r = unord((unsigned)(k2 >> 9));
        const int j = (int)(k2 & 511u);
        const float4 w0 = ((const float4*)&whL[j][0])[0];
        const float4 w1 = ((const float4*)&whL[j][0])[1];
        who[0] = w0.x; who[1] = w0.y; who[2] = w0.z; who[3] = w0.w;
        who[4] = w1.x; who[5] = w1.y; who[6] = w1.z; who[7] = w1.w;
        kH = lb512u(key1L, ((unsigned long long)(~(unsigned)(k2 >> 9))) << 9);
        e2p = __expf(s2r); e2q = __expf(LALPHA * s2r);
    }
    __syncthreads();                                           // B5

    // ---- P: finalize prefixes + pre-gather own payload row ----
    float pw = 0.f;
    if (!hi) {
        float offp = 0.f, offq = 0.f;
        #pragma unroll
        for (int ww = 0; ww < 8; ++ww) {
            const float tp = wvT[ww][0], tq = wvT[ww][1];
            if (ww < w) { offp += tp; offq += tq; }
        }
        prefP[t] = ps + offp;
        prefQ[t] = qs + offq;
        const unsigned long long k2 = key2L[t];
        const float s2p = unord((unsigned)(k2 >> 9));
        const int j2 = (int)(k2 & 511u);
        const float4 w0 = ((const float4*)&whL[j2][0])[0];
        const float4 w1 = ((const float4*)&whL[j2][0])[1];
        who[0] = w0.x; who[1] = w0.y; who[2] = w0.z; who[3] = w0.w;
        who[4] = w1.x; who[5] = w1.y; who[6] = w1.z; who[7] = w1.w;
        pw = __expf(s2p);
    }
    __syncthreads();                                           // B6

    // ---- H: denominators ----
    if (hi) {
        const float TPh = prefP[NN - 1];
        const float pk = kH ? prefP[kH - 1] : 0.f;
        const float qk = kH ? prefQ[kH - 1] : 0.f;
        const float den = e2p * (TPh - pk) + e2q * qk;
        denS[r] = den;
        pw = e2q / den;
    }
    __syncthreads();                                           // B7

    // ---- payload scans: P scans P-components, H scans Q-components ----
    float pv[NHID];
    if (!hi) pw /= denS[t];
    #pragma unroll
    for (int c = 0; c < NHID; ++c) pv[c] = wscan(pw * who[c], lane);
    if (lane == 63) {
        float4* wp = (float4*)&wvT[w][0];
        wp[0] = make_float4(pv[0], pv[1], pv[2], pv[3]);
        wp[1] = make_float4(pv[4], pv[5], pv[6], pv[7]);
    }
    __syncthreads();                                           // B8

    float tot[NHID];
    {
        const int wb = hi ? 8 : 0;
        float off[NHID];
        #pragma unroll
        for (int c = 0; c < NHID; ++c) { off[c] = 0.f; tot[c] = 0.f; }
        #pragma unroll
        for (int ww = 0; ww < 8; ++ww) {
            const float4 t0 = ((const float4*)&wvT[wb + ww][0])[0];
            const float4 t1 = ((const float4*)&wvT[wb + ww][0])[1];
            tot[0] += t0.x; tot[1] += t0.y; tot[2] += t0.z; tot[3] += t0.w;
            tot[4] += t1.x; tot[5] += t1.y; tot[6] += t1.z; tot[7] += t1.w;
            if (wb + ww < w) {
                off[0] += t0.x; off[1] += t0.y; off[2] += t0.z; off[3] += t0.w;
                off[4] += t1.x; off[5] += t1.y; off[6] += t1.z; off[7] += t1.w;
            }
        }
        #pragma unroll
        for (int c = 0; c < NHID; ++c) pv[c] += off[c];
        float4* dst = hi ? (float4*)&QQ[r][0] : (float4*)&PP[r][0];
        dst[0] = make_float4(pv[0], pv[1], pv[2], pv[3]);
        dst[1] = make_float4(pv[4], pv[5], pv[6], pv[7]);
    }
    __syncthreads();                                           // B9

    // ---- P: row outputs into registers ----
    float h0=0,h1=0,h2=0,h3=0,h4=0,h5=0,h6=0,h7=0;
    if (!hi) {
        float4 P0, P1, Q0, Q1;
        if (c4 > 0) {
            const float4* pp4 = (const float4*)&PP[c4 - 1][0];
            const float4* qq4 = (const float4*)&QQ[c4 - 1][0];
            P0 = pp4[0]; P1 = pp4[1]; Q0 = qq4[0]; Q1 = qq4[1];
        } else {
            P0 = P1 = Q0 = Q1 = make_float4(0.f, 0.f, 0.f, 0.f);
        }
        h0 = elu1(e1p * (tot[0] - P0.x) + e1q * Q0.x);
        h1 = elu1(e1p * (tot[1] - P0.y) + e1q * Q0.y);
        h2 = elu1(e1p * (tot[2] - P0.z) + e1q * Q0.z);
        h3 = elu1(e1p * (tot[3] - P0.w) + e1q * Q0.w);
        h4 = elu1(e1p * (tot[4] - P1.x) + e1q * Q1.x);
        h5 = elu1(e1p * (tot[5] - P1.y) + e1q * Q1.y);
        h6 = elu1(e1p * (tot[6] - P1.z) + e1q * Q1.z);
        h7 = elu1(e1p * (tot[7] - P1.w) + e1q * Q1.w);
    }
    __syncthreads();                                           // B10: all PP/QQ reads done

    if (!hi) {                                                 // stage output rows in PP
        float4* sp = (float4*)&PP[t][0];
        sp[0] = make_float4(h0, h1, h2, h3);
        sp[1] = make_float4(h4, h5, h6, h7);
    }
    __syncthreads();                                           // B11

    // coalesced 16 KB store: x2[h][b][*][*]
    {
        float4* xdst = (float4*)(x2 + (((size_t)h * 32 + b) * NN) * NHID);
        xdst[t] = ((const float4*)PP)[t];
    }
}

// Tail per batch b: Wh2 = x2@W_out (head-major reads); sort/scan; row-0 attn; head MLP.
// keyR1 padded so LDS > 80 KB: 1 block/CU -> 128-VGPR budget, no spills (grid is
// only 32 blocks, so occupancy is irrelevant; spill-avoidance is all that matters).
__global__ __launch_bounds__(1024) void k34_tail(
        const float* __restrict__ x2, const float* __restrict__ Wout,
        const float* __restrict__ aout, const float* __restrict__ feats,
        const float* __restrict__ l1w, const float* __restrict__ l1b,
        const float* __restrict__ pa, const float* __restrict__ gma,
        const float* __restrict__ bta, const float* __restrict__ l2w,
        const float* __restrict__ l2b, float* __restrict__ out)
{
    __shared__ __align__(16) float WLT[NHID * 64];             // transposed W_out [d][k], 2 KB
    __shared__ float aL[16];
    __shared__ __align__(16) float wh2[NN][NHID];              // 16 KB
    __shared__ __align__(16) float s1L[NN], s2L[NN];           // 4 KB
    __shared__ __align__(16) unsigned long long key1L[NN];     // 4 KB
    __shared__ __align__(16) unsigned long long keyR1[NN + 5888]; // 50 KB (runs + occupancy pad)
    __shared__ float prefP[NN], prefQ[NN];
    __shared__ float wvT[8][2];
    __shared__ float wR[8][NHID];
    __shared__ float hp[2][NHID];
    __shared__ float gatL[NHID];
    __shared__ float zL[NHID];
    // total ~82.4 KB > 80 KB -> 1 block/CU

    const int b = blockIdx.x, t = threadIdx.x;
    const int r = t & (NN - 1);
    const bool hi = t >= NN;
    const int lane = t & 63, w = t >> 6;
    const int wr = w & 7;
    const int cs = lane & 7;

    if (t < 512) {
        const int f = t >> 3, d = t & 7;
        WLT[d * 64 + f] = Wout[t];
    }
    if (t < 16) aL[t] = aout[t];
    __syncthreads();                                           // B1

    // matmul: 4 passes, 8 rows/wave, lane cs reads head cs's 8 floats of its row
    {
        const float4* x4 = (const float4*)x2;
        const float4* WT4 = (const float4*)WLT;
        #pragma unroll 2
        for (int pass = 0; pass < 4; ++pass) {
            const int row = pass * 128 + w * 8 + (lane >> 3);
            float acc[NHID];
            #pragma unroll
            for (int d = 0; d < NHID; ++d) acc[d] = 0.f;
            const int rb = (cs * 32 + b) * 1024 + row * 2;     // f4 base of x2[cs][b][row]
            #pragma unroll
            for (int i = 0; i < 2; ++i) {
                const float4 v = x4[rb + i];
                #pragma unroll
                for (int d = 0; d < NHID; ++d) {
                    const float4 wv = WT4[d * 16 + cs * 2 + i];
                    acc[d] += v.x * wv.x + v.y * wv.y + v.z * wv.z + v.w * wv.w;
                }
            }
            #pragma unroll
            for (int s = 1; s <= 4; s <<= 1) {
                #pragma unroll
                for (int d = 0; d < NHID; ++d) acc[d] += __shfl_xor(acc[d], s, 64);
            }
            if (cs == 0) {
                float4* wrp = (float4*)&wh2[row][0];
                wrp[0] = make_float4(acc[0], acc[1], acc[2], acc[3]);
                wrp[1] = make_float4(acc[4], acc[5], acc[6], acc[7]);
                float a1 = 0.f;
                #pragma unroll
                for (int d = 0; d < NHID; ++d) a1 += acc[d] * aL[d];
                s1L[row] = a1;
            } else if (cs == 1) {
                float a2 = 0.f;
                #pragma unroll
                for (int d = 0; d < NHID; ++d) a2 += acc[d] * aL[8 + d];
                s2L[row] = a2;
            }
        }
    }
    __syncthreads();                                           // B2

    // P: wave-sort s1 keys;  H (r<128): head feats dot
    unsigned long long sk = 0ull;
    if (!hi) {
        sk = (((unsigned long long)ordkey(s1L[t])) << 9) | (unsigned)t;
        sk = wsort64(sk, lane);
        keyR1[t] = sk;
    } else if (r < 128) {
        const float fk = feats[b * NFEAT + r];
        #pragma unroll
        for (int d = 0; d < NHID; ++d) {
            float p = fk * l1w[d * (NFEAT + NHID) + r];
            #pragma unroll
            for (int s = 1; s < 64; s <<= 1) p += __shfl_xor(p, s, 64);
            if (lane == 0) hp[w - 8][d] = p;
        }
    }
    __syncthreads();                                           // B3

    if (!hi) {
        const int rk = rank512(keyR1, sk, wr, lane);
        key1L[rk] = sk;
    }
    __syncthreads();                                           // B4

    // P: exp scans; H: c3 search
    float ps = 0.f, qs = 0.f;
    int c3 = 0; float v2h = 0.f, e2p = 0.f, e2q = 0.f;
    if (!hi) {
        const float s1v = unord((unsigned)(key1L[t] >> 9));
        ps = wscan(__expf(s1v), lane);
        qs = wscan(__expf(LALPHA * s1v), lane);
        if (lane == 63) { wvT[w][0] = ps; wvT[w][1] = qs; }
    } else {
        v2h = s2L[r];
        c3 = lb512u(key1L, ((unsigned long long)(~ordkey(v2h))) << 9);
        e2p = __expf(v2h); e2q = __expf(LALPHA * v2h);
    }
    __syncthreads();                                           // B5

    if (!hi) {
        float offp = 0.f, offq = 0.f;
        #pragma unroll
        for (int ww = 0; ww < 8; ++ww) {
            const float tp = wvT[ww][0], tq = wvT[ww][1];
            if (ww < w) { offp += tp; offq += tq; }
        }
        prefP[t] = ps + offp;
        prefQ[t] = qs + offq;
    }
    __syncthreads();                                           // B6

    // H: den + row-0 weight + weighted wave-reduce
    if (hi) {
        const float TPh = prefP[NN - 1];
        const float pk = c3 ? prefP[c3 - 1] : 0.f;
        const float qk = c3 ? prefQ[c3 - 1] : 0.f;
        const float dj = e2p * (TPh - pk) + e2q * qk;
        float e0 = s1L[0] + v2h;
        e0 = e0 >= 0.f ? e0 : LALPHA * e0;
        const float wgt = __expf(e0) / dj;
        float a[NHID];
        const float4 q0 = ((const float4*)&wh2[r][0])[0];
        const float4 q1 = ((const float4*)&wh2[r][0])[1];
        a[0] = wgt * q0.x; a[1] = wgt * q0.y; a[2] = wgt * q0.z; a[3] = wgt * q0.w;
        a[4] = wgt * q1.x; a[5] = wgt * q1.y; a[6] = wgt * q1.z; a[7] = wgt * q1.w;
        #pragma unroll
        for (int s = 1; s < 64; s <<= 1) {
            #pragma unroll
            for (int d = 0; d < NHID; ++d) a[d] += __shfl_xor(a[d], s, 64);
        }
        if (lane == 0) {
            #pragma unroll
            for (int d = 0; d < NHID; ++d) wR[w - 8][d] = a[d];
        }
    }
    __syncthreads();                                           // B7

    if (t < NHID) {
        float g = 0.f;
        #pragma unroll
        for (int ww = 0; ww < 8; ++ww) g += wR[ww][t];
        gatL[t] = elu1(g);
    }
    __syncthreads();                                           // B8

    if (t < NHID) {
        const float* wv = l1w + t * (NFEAT + NHID);
        float z = l1b[t] + hp[0][t] + hp[1][t];
        #pragma unroll
        for (int k = 0; k < NHID; ++k) z += gatL[k] * wv[NFEAT + k];
        const float a = pa[0];
        z = z >= 0.f ? z : a * z;
        z = z * (1.f / sqrtf(1.f + 1e-5f)) * gma[t] + bta[t];
        zL[t] = z;
    }
    __syncthreads();                                           // B9
    if (t == 0) {
        float o = l2b[0];
        #pragma unroll
        for (int d = 0; d < NHID; ++d) o += zL[d] * l2w[d];
        out[b] = o;
    }
}

extern "C" void kernel_launch(void* const* d_in, const int* in_sizes, int n_in,
                              void* d_out, int out_size, void* d_ws, size_t ws_size,
                              hipStream_t stream) {
    const float* feats = (const float*)d_in[0];
    const float* nf    = (const float*)d_in[1];
    const float* Ws    = (const float*)d_in[2];
    const float* As    = (const float*)d_in[3];
    const float* Wout  = (const float*)d_in[4];
    const float* aout  = (const float*)d_in[5];
    const float* l1w   = (const float*)d_in[6];
    const float* l1b   = (const float*)d_in[7];
    const float* pa    = (const float*)d_in[8];
    const float* gma   = (const float*)d_in[9];
    const float* bta   = (const float*)d_in[10];
    const float* l2w   = (const float*)d_in[11];
    const float* l2b   = (const float*)d_in[12];
    float* out = (float*)d_out;

    float* x2 = (float*)d_ws;   // head-major: 8*32*512*8 floats = 4 MB

    k12_gat1<<<BB * NHEADS, 1024, 0, stream>>>(nf, Ws, As, x2);
    k34_tail<<<BB, 1024, 0, stream>>>(x2, Wout, aout, feats, l1w, l1b, pa, gma, bta, l2w, l2b, out);
}

// Round 13
// 39.829 us; speedup vs baseline: 2.3800x; 2.3800x over previous
//
#include <hip/hip_runtime.h>
#include <math.h>

#define BB 32
#define NN 512
#define NFEAT 128
#define NHID 8
#define NHEADS 8
#define LALPHA 0.2f

__device__ __forceinline__ float elu1(float x)  { return x > 0.f ? x : __expf(x) - 1.f; }

// monotone float -> uint mapping (total order refines float order); ok(-v) == ~ok(v)
__device__ __forceinline__ unsigned ordkey(float v) {
    unsigned u = __float_as_uint(v);
    return u ^ (((unsigned)((int)u >> 31)) | 0x80000000u);
}
__device__ __forceinline__ float unord(unsigned k) {
    unsigned u = (k & 0x80000000u) ? (k ^ 0x80000000u) : ~k;
    return __uint_as_float(u);
}

// inclusive 64-lane add-scan: 6 DPP ops (VALU pipe only).
#if __has_builtin(__builtin_amdgcn_update_dpp)
__device__ __forceinline__ float wscan(float x, int lane) {
    int y;
    y = __builtin_amdgcn_update_dpp(0, __float_as_int(x), 0x111, 0xF, 0xF, true); x += __int_as_float(y);
    y = __builtin_amdgcn_update_dpp(0, __float_as_int(x), 0x112, 0xF, 0xF, true); x += __int_as_float(y);
    y = __builtin_amdgcn_update_dpp(0, __float_as_int(x), 0x114, 0xF, 0xF, true); x += __int_as_float(y);
    y = __builtin_amdgcn_update_dpp(0, __float_as_int(x), 0x118, 0xF, 0xF, true); x += __int_as_float(y);
    y = __builtin_amdgcn_update_dpp(0, __float_as_int(x), 0x142, 0xA, 0xF, true); x += __int_as_float(y);
    y = __builtin_amdgcn_update_dpp(0, __float_as_int(x), 0x143, 0xC, 0xF, true); x += __int_as_float(y);
    return x;
}
#else
__device__ __forceinline__ float wscan(float x, int lane) {
    #pragma unroll
    for (int s = 1; s < 64; s <<= 1) {
        float y = __shfl_up(x, (unsigned)s, 64);
        x += (lane >= s) ? y : 0.f;
    }
    return x;
}
#endif

__device__ __forceinline__ unsigned long long shflxor64(unsigned long long x, int j) {
    unsigned lo = (unsigned)__shfl_xor((int)(unsigned)x, j, 64);
    unsigned hw = (unsigned)__shfl_xor((int)(unsigned)(x >> 32), j, 64);
    return (((unsigned long long)hw) << 32) | lo;
}

// full in-wave bitonic sort of 64 u64 keys (ascending across lanes), register-only
__device__ __forceinline__ unsigned long long wsort64(unsigned long long x, int lane) {
    #pragma unroll
    for (int k = 2; k <= 64; k <<= 1) {
        #pragma unroll
        for (int j = k >> 1; j >= 1; j >>= 1) {
            unsigned long long y = shflxor64(x, j);
            const bool takeMin = ((lane & j) == 0) == ((lane & k) == 0);
            const bool sw = takeMin ? (y < x) : (x < y);
            x = sw ? y : x;
        }
    }
    return x;
}

// guarded branchless lower bounds (can return the full length)
__device__ __forceinline__ int lb64u(const unsigned long long* a, unsigned long long v) {
    int lo = 0;
    #pragma unroll
    for (int s = 64; s >= 1; s >>= 1) {
        const int i2 = lo + s - 1;
        if (i2 < 64 && a[i2] < v) lo += s;
    }
    return lo;
}
__device__ __forceinline__ int lb512u(const unsigned long long* a, unsigned long long v) {
    int lo = 0;
    #pragma unroll
    for (int s = NN; s >= 1; s >>= 1) {
        const int i2 = lo + s - 1;
        if (i2 < NN && a[i2] < v) lo += s;
    }
    return lo;
}

// global rank of x within the 8 sorted runs (own wave-run index wr, own lane pos = lane)
__device__ __forceinline__ int rank512(const unsigned long long* runs, unsigned long long x,
                                       int wr, int lane) {
    int rk = lane;
    #pragma unroll
    for (int w2 = 0; w2 < 8; ++w2)
        if (w2 != wr) rk += lb64u(runs + 64 * w2, x);
    return rk;
}

// Fused layer-1 GAT per (b,h). 1024 threads: P (t<512) and H (t>=512) run different phases.
// Block->(b,h) mapping: b = blk&31, h = blk>>5 so all 8 heads of batch b run on XCD b%8
// (nf[b] is fetched into exactly one XCD's L2). LDS ~91 KB -> naturally 1 block/CU,
// which keeps the VGPR budget at 4 waves/SIMD (128) — round 7 measured VGPR 52, no spills.
__global__ __launch_bounds__(1024) void k12_gat1(
        const float* __restrict__ nf, const float* __restrict__ Ws,
        const float* __restrict__ As, float* __restrict__ x)
{
    __shared__ __align__(16) float WT[NHID * NFEAT];           // transposed W [d][f], 4 KB
    __shared__ float aL[16];
    __shared__ __align__(16) float whL[NN][NHID];              // 16 KB
    __shared__ __align__(16) float part[NN][NHID];             // 16 KB
    __shared__ __align__(16) unsigned long long key1L[NN];     // 4 KB (sorted s1 keys)
    __shared__ __align__(16) unsigned long long key2L[NN];     // 4 KB (sorted s2 keys)
    __shared__ __align__(16) unsigned long long keyR1[NN];     // 4 KB (8 sorted runs)
    __shared__ __align__(16) unsigned long long keyR2[NN];     // 4 KB
    __shared__ float prefP[NN], prefQ[NN], denS[NN];
    __shared__ __align__(16) float PP[NN][NHID];               // 16 KB
    __shared__ __align__(16) float QQ[NN][NHID];               // 16 KB
    __shared__ __align__(16) float wvT[16][NHID];

    const int blk = blockIdx.x;
    const int b = blk & 31, h = blk >> 5;   // XCD swizzle: blk%8 == b%8
    const int t = threadIdx.x;
    const int r = t & (NN - 1);
    const bool hi = t >= NN;
    const int lane = t & 63, w = t >> 6;
    const int wr = w & 7;                   // run index within own half

    {
        const int f = t >> 3, d = t & 7;
        WT[d * NFEAT + f] = Ws[(size_t)h * NFEAT * NHID + t];
    }
    if (t < 16) aL[t] = As[h * 16 + t];
    __syncthreads();                                           // B1

    // ---- matmul, split K: P cols [0,64), H cols [64,128) ----
    float acc[NHID];
    {
        #pragma unroll
        for (int d = 0; d < NHID; ++d) acc[d] = 0.f;
        const float4* row = (const float4*)(nf + ((size_t)b * NN + r) * NFEAT + (hi ? 64 : 0));
        const int fb = hi ? 16 : 0;
        const float4* WT4 = (const float4*)WT;
        #pragma unroll 4
        for (int f4 = 0; f4 < 16; ++f4) {
            float4 v = row[f4];
            #pragma unroll
            for (int d = 0; d < NHID; ++d) {
                float4 wv = WT4[d * 32 + fb + f4];
                acc[d] += v.x * wv.x + v.y * wv.y + v.z * wv.z + v.w * wv.w;
            }
        }
        if (hi) {
            float4* pp = (float4*)&part[r][0];
            pp[0] = make_float4(acc[0], acc[1], acc[2], acc[3]);
            pp[1] = make_float4(acc[4], acc[5], acc[6], acc[7]);
        }
    }
    __syncthreads();                                           // B2

    float v1 = 0.f;
    unsigned long long sk = 0ull;
    if (!hi) {
        #pragma unroll
        for (int d = 0; d < NHID; ++d) acc[d] += part[t][d];
        float a1 = 0.f, a2 = 0.f;
        #pragma unroll
        for (int d = 0; d < NHID; ++d) { a1 += acc[d] * aL[d]; a2 += acc[d] * aL[8 + d]; }
        v1 = a1;
        float4* wrp = (float4*)&whL[t][0];
        wrp[0] = make_float4(acc[0], acc[1], acc[2], acc[3]);
        wrp[1] = make_float4(acc[4], acc[5], acc[6], acc[7]);
        sk = (((unsigned long long)ordkey(a1)) << 9) | (unsigned)t;
        key2L[t] = (((unsigned long long)ordkey(a2)) << 9) | (unsigned)t;
    }
    __syncthreads();                                           // B3

    // ---- wave-local sorts (register-only), write sorted runs ----
    if (hi) sk = key2L[r];
    sk = wsort64(sk, lane);
    if (!hi) keyR1[t] = sk; else keyR2[r] = sk;
    __syncthreads();                                           // B4

    // ---- rank-merge + scatter into final sorted arrays ----
    {
        const unsigned long long* runs = hi ? keyR2 : keyR1;
        const int rk = rank512(runs, sk, wr, lane);
        if (!hi) key1L[rk] = sk; else key2L[rk] = sk;
    }
    __syncthreads();                                           // B5

    // ---- P: exp scans + c4; H: own sorted element, payload gather + kH ----
    float ps = 0.f, qs = 0.f;
    float who[NHID];
    float s2r = 0.f, e2p = 0.f, e2q = 0.f, e1p = 0.f, e1q = 0.f;
    int kH = 0, c4 = 0;
    if (!hi) {
        const float s1v = unord((unsigned)(key1L[t] >> 9));
        ps = wscan(__expf(s1v), lane);
        qs = wscan(__expf(LALPHA * s1v), lane);
        if (lane == 63) { wvT[w][0] = ps; wvT[w][1] = qs; }
        c4 = lb512u(key2L, ((unsigned long long)(~ordkey(v1))) << 9);
        e1p = __expf(v1); e1q = __expf(LALPHA * v1);
    } else {
        const unsigned long long k2 = key2L[r];
        s2r = unord((unsigned)(k2 >> 9));
        const int j = (int)(k2 & 511u);
        const float4 w0 = ((const float4*)&whL[j][0])[0];
        const float4 w1 = ((const float4*)&whL[j][0])[1];
        who[0] = w0.x; who[1] = w0.y; who[2] = w0.z; who[3] = w0.w;
        who[4] = w1.x; who[5] = w1.y; who[6] = w1.z; who[7] = w1.w;
        kH = lb512u(key1L, ((unsigned long long)(~(unsigned)(k2 >> 9))) << 9);
        e2p = __expf(s2r); e2q = __expf(LALPHA * s2r);
    }
    __syncthreads();                                           // B6

    // ---- P: finalize prefixes + pre-gather own payload row ----
    float pw = 0.f;
    if (!hi) {
        float offp = 0.f, offq = 0.f;
        #pragma unroll
        for (int ww = 0; ww < 8; ++ww) {
            const float tp = wvT[ww][0], tq = wvT[ww][1];
            if (ww < w) { offp += tp; offq += tq; }
        }
        prefP[t] = ps + offp;
        prefQ[t] = qs + offq;
        const unsigned long long k2 = key2L[t];
        const float s2p = unord((unsigned)(k2 >> 9));
        const int j2 = (int)(k2 & 511u);
        const float4 w0 = ((const float4*)&whL[j2][0])[0];
        const float4 w1 = ((const float4*)&whL[j2][0])[1];
        who[0] = w0.x; who[1] = w0.y; who[2] = w0.z; who[3] = w0.w;
        who[4] = w1.x; who[5] = w1.y; who[6] = w1.z; who[7] = w1.w;
        pw = __expf(s2p);
    }
    __syncthreads();                                           // B7

    // ---- H: denominators ----
    if (hi) {
        const float TPh = prefP[NN - 1];
        const float pk = kH ? prefP[kH - 1] : 0.f;
        const float qk = kH ? prefQ[kH - 1] : 0.f;
        const float den = e2p * (TPh - pk) + e2q * qk;
        denS[r] = den;
        pw = e2q / den;
    }
    __syncthreads();                                           // B8

    // ---- payload scans: P scans P-components, H scans Q-components ----
    float pv[NHID];
    if (!hi) pw /= denS[t];
    #pragma unroll
    for (int c = 0; c < NHID; ++c) pv[c] = wscan(pw * who[c], lane);
    if (lane == 63) {
        float4* wp = (float4*)&wvT[w][0];
        wp[0] = make_float4(pv[0], pv[1], pv[2], pv[3]);
        wp[1] = make_float4(pv[4], pv[5], pv[6], pv[7]);
    }
    __syncthreads();                                           // B9

    float tot[NHID];
    {
        const int wb = hi ? 8 : 0;
        float off[NHID];
        #pragma unroll
        for (int c = 0; c < NHID; ++c) { off[c] = 0.f; tot[c] = 0.f; }
        #pragma unroll
        for (int ww = 0; ww < 8; ++ww) {
            const float4 t0 = ((const float4*)&wvT[wb + ww][0])[0];
            const float4 t1 = ((const float4*)&wvT[wb + ww][0])[1];
            tot[0] += t0.x; tot[1] += t0.y; tot[2] += t0.z; tot[3] += t0.w;
            tot[4] += t1.x; tot[5] += t1.y; tot[6] += t1.z; tot[7] += t1.w;
            if (wb + ww < w) {
                off[0] += t0.x; off[1] += t0.y; off[2] += t0.z; off[3] += t0.w;
                off[4] += t1.x; off[5] += t1.y; off[6] += t1.z; off[7] += t1.w;
            }
        }
        #pragma unroll
        for (int c = 0; c < NHID; ++c) pv[c] += off[c];
        float4* dst = hi ? (float4*)&QQ[r][0] : (float4*)&PP[r][0];
        dst[0] = make_float4(pv[0], pv[1], pv[2], pv[3]);
        dst[1] = make_float4(pv[4], pv[5], pv[6], pv[7]);
    }
    __syncthreads();                                           // B10

    // ---- P: row outputs ----
    if (!hi) {
        float4 P0, P1, Q0, Q1;
        if (c4 > 0) {
            const float4* pp4 = (const float4*)&PP[c4 - 1][0];
            const float4* qq4 = (const float4*)&QQ[c4 - 1][0];
            P0 = pp4[0]; P1 = pp4[1]; Q0 = qq4[0]; Q1 = qq4[1];
        } else {
            P0 = P1 = Q0 = Q1 = make_float4(0.f, 0.f, 0.f, 0.f);
        }
        float h0 = e1p * (tot[0] - P0.x) + e1q * Q0.x;
        float h1 = e1p * (tot[1] - P0.y) + e1q * Q0.y;
        float h2 = e1p * (tot[2] - P0.z) + e1q * Q0.z;
        float h3 = e1p * (tot[3] - P0.w) + e1q * Q0.w;
        float h4 = e1p * (tot[4] - P1.x) + e1q * Q1.x;
        float h5 = e1p * (tot[5] - P1.y) + e1q * Q1.y;
        float h6 = e1p * (tot[6] - P1.z) + e1q * Q1.z;
        float h7 = e1p * (tot[7] - P1.w) + e1q * Q1.w;
        float* xp = x + ((size_t)(b * NN + t)) * (NHEADS * NHID) + h * NHID;
        ((float4*)xp)[0] = make_float4(elu1(h0), elu1(h1), elu1(h2), elu1(h3));
        ((float4*)xp)[1] = make_float4(elu1(h4), elu1(h5), elu1(h6), elu1(h7));
    }
}

// Tail per batch b: Wh2 = x@W_out; wave-sort + rank-merge of s1; row-0 attn; head MLP.
__global__ __launch_bounds__(1024) void k34_tail(
        const float* __restrict__ x, const float* __restrict__ Wout,
        const float* __restrict__ aout, const float* __restrict__ feats,
        const float* __restrict__ l1w, const float* __restrict__ l1b,
        const float* __restrict__ pa, const float* __restrict__ gma,
        const float* __restrict__ bta, const float* __restrict__ l2w,
        const float* __restrict__ l2b, float* __restrict__ out)
{
    __shared__ __align__(16) float WLT[NHID * 64];             // transposed W_out [d][f], 2 KB
    __shared__ float aL[16];
    __shared__ __align__(16) float wh2[NN][NHID];              // 16 KB
    __shared__ __align__(16) float part[NN][NHID];             // 16 KB
    __shared__ __align__(16) unsigned long long key1L[NN];     // 4 KB
    __shared__ __align__(16) unsigned long long keyR1[NN];     // 4 KB
    __shared__ float s2L[NN];
    __shared__ float prefP[NN], prefQ[NN];
    __shared__ float wvT[8][2];
    __shared__ float wR[8][NHID];
    __shared__ float hp[2][NHID];
    __shared__ float gatL[NHID];
    __shared__ float zL[NHID];
    __shared__ float s1zero;

    const int b = blockIdx.x, t = threadIdx.x;
    const int r = t & (NN - 1);
    const bool hi = t >= NN;
    const int lane = t & 63, w = t >> 6;
    const int wr = w & 7;

    if (t < 512) {
        const int f = t >> 3, d = t & 7;
        WLT[d * 64 + f] = Wout[t];
    }
    if (t < 16) aL[t] = aout[t];
    __syncthreads();                                           // B1

    // matmul, split K: P cols [0,32), H cols [32,64)
    float acc[NHID];
    {
        #pragma unroll
        for (int d = 0; d < NHID; ++d) acc[d] = 0.f;
        const float4* row = (const float4*)(x + ((size_t)b * NN + r) * (NHEADS * NHID) + (hi ? 32 : 0));
        const int fb = hi ? 8 : 0;
        const float4* WT4 = (const float4*)WLT;
        #pragma unroll 4
        for (int f4 = 0; f4 < 8; ++f4) {
            float4 v = row[f4];
            #pragma unroll
            for (int d = 0; d < NHID; ++d) {
                float4 wv = WT4[d * 16 + fb + f4];
                acc[d] += v.x * wv.x + v.y * wv.y + v.z * wv.z + v.w * wv.w;
            }
        }
        if (hi) {
            float4* pp = (float4*)&part[r][0];
            pp[0] = make_float4(acc[0], acc[1], acc[2], acc[3]);
            pp[1] = make_float4(acc[4], acc[5], acc[6], acc[7]);
        }
    }
    __syncthreads();                                           // B2

    unsigned long long sk = 0ull;
    if (!hi) {
        #pragma unroll
        for (int d = 0; d < NHID; ++d) acc[d] += part[t][d];
        float a1 = 0.f, a2 = 0.f;
        #pragma unroll
        for (int d = 0; d < NHID; ++d) { a1 += acc[d] * aL[d]; a2 += acc[d] * aL[8 + d]; }
        float4* wrp = (float4*)&wh2[t][0];
        wrp[0] = make_float4(acc[0], acc[1], acc[2], acc[3]);
        wrp[1] = make_float4(acc[4], acc[5], acc[6], acc[7]);
        sk = (((unsigned long long)ordkey(a1)) << 9) | (unsigned)t;
        s2L[t] = a2;
        if (t == 0) s1zero = a1;
    }
    __syncthreads();                                           // B3

    // P: wave-sort + write runs;  H (r<128): head feats dot
    if (!hi) {
        sk = wsort64(sk, lane);
        keyR1[t] = sk;
    } else if (r < 128) {
        const float fk = feats[b * NFEAT + r];
        #pragma unroll
        for (int d = 0; d < NHID; ++d) {
            float p = fk * l1w[d * (NFEAT + NHID) + r];
            #pragma unroll
            for (int s = 1; s < 64; s <<= 1) p += __shfl_xor(p, s, 64);
            if (lane == 0) hp[w - 8][d] = p;
        }
    }
    __syncthreads();                                           // B4

    if (!hi) {
        const int rk = rank512(keyR1, sk, wr, lane);
        key1L[rk] = sk;
    }
    __syncthreads();                                           // B5

    // P: exp scans; H: c3 search
    float ps = 0.f, qs = 0.f;
    int c3 = 0; float v2h = 0.f, e2p = 0.f, e2q = 0.f;
    if (!hi) {
        const float s1v = unord((unsigned)(key1L[t] >> 9));
        ps = wscan(__expf(s1v), lane);
        qs = wscan(__expf(LALPHA * s1v), lane);
        if (lane == 63) { wvT[w][0] = ps; wvT[w][1] = qs; }
    } else {
        v2h = s2L[r];
        c3 = lb512u(key1L, ((unsigned long long)(~ordkey(v2h))) << 9);
        e2p = __expf(v2h); e2q = __expf(LALPHA * v2h);
    }
    __syncthreads();                                           // B6

    if (!hi) {
        float offp = 0.f, offq = 0.f;
        #pragma unroll
        for (int ww = 0; ww < 8; ++ww) {
            const float tp = wvT[ww][0], tq = wvT[ww][1];
            if (ww < w) { offp += tp; offq += tq; }
        }
        prefP[t] = ps + offp;
        prefQ[t] = qs + offq;
    }
    __syncthreads();                                           // B7

    // H: den + row-0 weight + weighted wave-reduce
    if (hi) {
        const float TPh = prefP[NN - 1];
        const float pk = c3 ? prefP[c3 - 1] : 0.f;
        const float qk = c3 ? prefQ[c3 - 1] : 0.f;
        const float dj = e2p * (TPh - pk) + e2q * qk;
        float e0 = s1zero + v2h;
        e0 = e0 >= 0.f ? e0 : LALPHA * e0;
        const float wgt = __expf(e0) / dj;
        float a[NHID];
        const float4 q0 = ((const float4*)&wh2[r][0])[0];
        const float4 q1 = ((const float4*)&wh2[r][0])[1];
        a[0] = wgt * q0.x; a[1] = wgt * q0.y; a[2] = wgt * q0.z; a[3] = wgt * q0.w;
        a[4] = wgt * q1.x; a[5] = wgt * q1.y; a[6] = wgt * q1.z; a[7] = wgt * q1.w;
        #pragma unroll
        for (int s = 1; s < 64; s <<= 1) {
            #pragma unroll
            for (int d = 0; d < NHID; ++d) a[d] += __shfl_xor(a[d], s, 64);
        }
        if (lane == 0) {
            #pragma unroll
            for (int d = 0; d < NHID; ++d) wR[w - 8][d] = a[d];
        }
    }
    __syncthreads();                                           // B8

    if (t < NHID) {
        float g = 0.f;
        #pragma unroll
        for (int ww = 0; ww < 8; ++ww) g += wR[ww][t];
        gatL[t] = elu1(g);
    }
    __syncthreads();                                           // B9

    if (t < NHID) {
        const float* wv = l1w + t * (NFEAT + NHID);
        float z = l1b[t] + hp[0][t] + hp[1][t];
        #pragma unroll
        for (int k = 0; k < NHID; ++k) z += gatL[k] * wv[NFEAT + k];
        const float a = pa[0];
        z = z >= 0.f ? z : a * z;
        z = z * (1.f / sqrtf(1.f + 1e-5f)) * gma[t] + bta[t];
        zL[t] = z;
    }
    __syncthreads();                                           // B10
    if (t == 0) {
        float o = l2b[0];
        #pragma unroll
        for (int d = 0; d < NHID; ++d) o += zL[d] * l2w[d];
        out[b] = o;
    }
}

extern "C" void kernel_launch(void* const* d_in, const int* in_sizes, int n_in,
                              void* d_out, int out_size, void* d_ws, size_t ws_size,
                              hipStream_t stream) {
    const float* feats = (const float*)d_in[0];
    const float* nf    = (const float*)d_in[1];
    const float* Ws    = (const float*)d_in[2];
    const float* As    = (const float*)d_in[3];
    const float* Wout  = (const float*)d_in[4];
    const float* aout  = (const float*)d_in[5];
    const float* l1w   = (const float*)d_in[6];
    const float* l1b   = (const float*)d_in[7];
    const float* pa    = (const float*)d_in[8];
    const float* gma   = (const float*)d_in[9];
    const float* bta   = (const float*)d_in[10];
    const float* l2w   = (const float*)d_in[11];
    const float* l2b   = (const float*)d_in[12];
    float* out = (float*)d_out;

    float* x = (float*)d_ws;   // 32*512*64 floats = 4 MB

    k12_gat1<<<BB * NHEADS, 1024, 0, stream>>>(nf, Ws, As, x);
    k34_tail<<<BB, 1024, 0, stream>>>(x, Wout, aout, feats, l1w, l1b, pa, gma, bta, l2w, l2b, out);
}